// Round 6
// baseline (263.343 us; speedup 1.0000x reference)
//
#include <hip/hip_runtime.h>

// TemporalLSTM round 15 (gfx950): 2-wave cooperative cell-split.
//
// R14 post-mortem (REGRESSED 180->201): x-proj hoist alone is poison (VGPR
// 136, more movs, worse schedule). R10/R12/R13/R14 together prove: at 1
// wave/SIMD no source reordering creates overlap. Step ~2160 cyc = trans
// ~832 + VALU ~460 + matrix ~546 (17cyc/MFMA single-wave occupancy floor,
// R13) + stalls: ONE instruction stream can't fill two pipes.
//
// R15: second stream. 2 waves/block SHARE the 16 batches, split by cell
// half (hb): wave w owns tiles t8=4w+g (4 xg + 12 h MFMAs) and the
// pointwise of cells j=8q+4w+r (2 pairs, 26 trans). Per-step exchange of
// the other half's h: one uint4/lane (2 Bh + 2 Bl words) via double-
// buffered LDS, ONE barrier/step. Same rows, same per-tile accumulation
// order, same rcp pairings as R13 -> bit-identical output.
// 1024 blocks x 128 thr = 2048 waves = 2/SIMD (R8's failure was halving
// batches -- wave-wide cost didn't halve; this split halves per-wave work).
//
// Structure recap (verified R5): A = weights (resident VGPR frags), B = h.
// Gate-row permutation  tile t8 = hb*4+g :  row m -> R = 32g + 8*(m>>2) + 4*hb + (m&3)
// gives C/D (m=4q+r, n): acc[g][r] = gate g, batch col n, cell j = 8q+4*wid+r.

typedef __bf16 bf16x8 __attribute__((ext_vector_type(8)));
typedef float  f32x4  __attribute__((ext_vector_type(4)));
typedef float  f32x2  __attribute__((ext_vector_type(2)));
typedef unsigned int u32;

constexpr int kT = 200, kIN = 5, kH = 32;
constexpr int CT = 40;   // timesteps of x staged per phase (200 = 5*40)

constexpr float kL  = 1.4426950408889634f;   // log2(e)
constexpr float k2L = 2.8853900817779268f;   // 2*log2(e)

union FragU { bf16x8 v; __bf16 b[8]; unsigned short s[8]; u32 u[4]; uint4 q4; };

__device__ __forceinline__ unsigned short bfbits(__bf16 b) {
    union { __bf16 b; unsigned short s; } u; u.b = b; return u.s;
}
__device__ __forceinline__ void split2(float x, __bf16& hi, __bf16& lo) {
    hi = (__bf16)x;                 // RNE cvt
    lo = (__bf16)(x - (float)hi);   // residual, |lo| <= 2^-9 |x|
}
// pack two f32 -> one u32 of 2xbf16 (RNE per element; canonical cvt_pk shape)
__device__ __forceinline__ u32 pkbf(float a, float b) {
    return (u32)bfbits((__bf16)a) | ((u32)bfbits((__bf16)b) << 16);
}
__device__ __forceinline__ float f_from_bits(u32 x) {
    union { u32 u; float f; } t; t.u = x; return t.f;
}

__global__ __launch_bounds__(128) void lstm_dw(
    const float* __restrict__ x,     // [B,200,5]
    const float* __restrict__ W_ih,  // [128,5]
    const float* __restrict__ W_hh,  // [128,32]
    const float* __restrict__ b_ih,  // [128]
    const float* __restrict__ b_hh,  // [128]
    const float* __restrict__ W_fc,  // [2,32]
    const float* __restrict__ b_fc,  // [2]
    float* __restrict__ out)         // [B,2]
{
    __shared__ uint4 xbuf[CT][34];     // cols 0..31: x B-frags; 32/33: const quads
    __shared__ uint4 xch[2][2][64];    // [step parity][wave][lane]: h exchange

    const int tid  = threadIdx.x;
    const int wid  = tid >> 6;         // wave id: 0 -> cells kk 0..3, 1 -> 4..7
    const int lane = tid & 63;
    const int n16  = lane & 15;
    const int q    = lane >> 4;
    const int b0   = blockIdx.x * 16;

    // ---- weight A-frags: 4 tiles per wave (t8 = 4*wid + g) ----
    // Scaled by kL (gates i,f,o) or k2L (gate g) BEFORE the hi/lo split, so acc
    // values are exp2-ready.
    bf16x8 whhA_h[4], whhA_l[4], wihA[4];
#pragma unroll
    for (int g = 0; g < 4; ++g) {
        const int R = g * 32 + 8 * (n16 >> 2) + 4 * wid + (n16 & 3);  // gate row
        const float sc = (g == 2) ? k2L : kL;
        FragU H, L;
#pragma unroll
        for (int j = 0; j < 8; ++j)
            split2(sc * W_hh[R * kH + q * 8 + j], H.b[j], L.b[j]);
        whhA_h[g] = H.v; whhA_l[g] = L.v;

        float wr[5];
#pragma unroll
        for (int i = 0; i < 5; ++i) wr[i] = sc * W_ih[R * kIN + i];
        __bf16 bh, bl;
        split2(sc * (b_ih[R] + b_hh[R]), bh, bl);

        FragU F;
        F.u[0] = F.u[1] = F.u[2] = F.u[3] = 0u;
        if (q == 0) {                       // k0..7
#pragma unroll
            for (int i = 0; i < 5; ++i) F.b[i] = (__bf16)wr[i];       // k0..4: Wih_hi
#pragma unroll
            for (int i = 0; i < 3; ++i) F.b[5 + i] = (__bf16)wr[i];   // k5..7: Wih_hi(0..2)
        } else if (q == 1) {                // k8..15
            F.b[0] = (__bf16)wr[3];                                   // k8:  Wih_hi(3)
            F.b[1] = (__bf16)wr[4];                                   // k9:  Wih_hi(4)
#pragma unroll
            for (int i = 0; i < 5; ++i) {                             // k10..14: Wih_lo
                __bf16 hbb, lbb; split2(wr[i], hbb, lbb);
                F.b[2 + i] = lbb;
            }
            F.b[7] = bh;                                              // k15: bias_hi
        } else if (q == 2) {
            F.b[0] = bl;                                              // k16: bias_lo
        }
        wihA[g] = F.v;
    }

    // ---- const x-frag quads + exchange-buffer zero-init (once) ----
    for (int t2 = tid; t2 < CT; t2 += 128) {
        xbuf[t2][32] = make_uint4(0x3F80u, 0u, 0u, 0u);   // quad2: k16 B=1.0 (bf16)
        xbuf[t2][33] = make_uint4(0u, 0u, 0u, 0u);        // quad3: zeros
    }
    xch[0][wid][lane] = make_uint4(0u, 0u, 0u, 0u);
    xch[1][wid][lane] = make_uint4(0u, 0u, 0u, 0u);       // read at tc=0 (h=0)

    const int col = (q < 2) ? (n16 * 2 + q) : (30 + q);   // loop-invariant frag column
    const f32x4 zf4 = {0.f, 0.f, 0.f, 0.f};

    // recurrence state (own 4 cells). c in 2L units (c_scaled = 2L*c).
    f32x2 c4v[2] = {{0.f, 0.f}, {0.f, 0.f}};
    u32 bh_own[2] = {0u, 0u};          // own Bh words (cells kk 4w+0..3)
    u32 bl_own[2] = {0u, 0u};

    for (int phase = 0; phase < kT / CT; ++phase) {
        // ---- stage CT steps of x as ready-made B-frags (wave 0 only) ----
        if (wid == 0) {
            const int mm = lane >> 2, pp = lane & 3;       // batch row, 10-step chunk
            const float2* xr2 = (const float2*)(x + (size_t)(b0 + mm) * (kT * kIN)
                                                  + (size_t)(phase * CT + pp * 10) * kIN);
            float xv[50];
#pragma unroll
            for (int i = 0; i < 25; ++i) {
                float2 v = xr2[i];
                xv[2 * i] = v.x; xv[2 * i + 1] = v.y;
            }
#pragma unroll
            for (int s5 = 0; s5 < 10; ++s5) {
                u32 xh[5], xl[5];
#pragma unroll
                for (int i = 0; i < 5; ++i) {
                    __bf16 hbb, lbb; split2(xv[s5 * 5 + i], hbb, lbb);
                    xh[i] = bfbits(hbb); xl[i] = bfbits(lbb);
                }
                uint4 f0 = make_uint4(xh[0] | (xh[1] << 16),
                                      xh[2] | (xh[3] << 16),
                                      xh[4] | (xl[0] << 16),
                                      xl[1] | (xl[2] << 16));
                uint4 f1 = make_uint4(xl[3] | (xl[4] << 16),
                                      xh[0] | (xh[1] << 16),
                                      xh[2] | (xh[3] << 16),
                                      xh[4] | (0x3F80u << 16));   // k15: B = 1.0
                const int tc = pp * 10 + s5;
                xbuf[tc][mm * 2 + 0] = f0;
                xbuf[tc][mm * 2 + 1] = f1;
            }
        }
        __syncthreads();

        FragU xg; xg.q4 = xbuf[0][col];

#pragma unroll 1
        for (int tc = 0; tc < CT; ++tc) {
            // prefetch next step's xg (dummy wrap at tc=CT-1, reloaded fresh
            // after the next phase's staging barrier)
            FragU xgn;
            const int tn = (tc + 1 < CT) ? tc + 1 : 0;
            xgn.q4 = xbuf[tn][col];

            // assemble full h B-frags: own half (regs) + other half (LDS,
            // written by the partner wave at the end of step tc-1, barrier'd)
            const uint4 oth = xch[(tc ^ 1) & 1][wid ^ 1][lane];
            FragU BhF, BlF;
            if (wid == 0) {
                BhF.u[0] = bh_own[0]; BhF.u[1] = bh_own[1];
                BhF.u[2] = oth.x;     BhF.u[3] = oth.y;
                BlF.u[0] = bl_own[0]; BlF.u[1] = bl_own[1];
                BlF.u[2] = oth.z;     BlF.u[3] = oth.w;
            } else {
                BhF.u[0] = oth.x;     BhF.u[1] = oth.y;
                BhF.u[2] = bh_own[0]; BhF.u[3] = bh_own[1];
                BlF.u[0] = oth.z;     BlF.u[1] = oth.w;
                BlF.u[2] = bl_own[0]; BlF.u[3] = bl_own[1];
            }

            // gates: stage-major, 4 tiles. Per-tile accumulation order
            // (xg -> hh*Bh -> hh*Bl -> hl*Bh) unchanged -> bit-identical.
            f32x4 acc[4];
#pragma unroll
            for (int g = 0; g < 4; ++g)
                acc[g] = __builtin_amdgcn_mfma_f32_16x16x32_bf16(wihA[g], xg.v, zf4, 0, 0, 0);
#pragma unroll
            for (int g = 0; g < 4; ++g)
                acc[g] = __builtin_amdgcn_mfma_f32_16x16x32_bf16(whhA_h[g], BhF.v, acc[g], 0, 0, 0);
#pragma unroll
            for (int g = 0; g < 4; ++g)
                acc[g] = __builtin_amdgcn_mfma_f32_16x16x32_bf16(whhA_h[g], BlF.v, acc[g], 0, 0, 0);
#pragma unroll
            for (int g = 0; g < 4; ++g)
                acc[g] = __builtin_amdgcn_mfma_f32_16x16x32_bf16(whhA_l[g], BhF.v, acc[g], 0, 0, 0);

            // pointwise: 2 pairs (cells r = 2p, 2p+1). Same pair groupings
            // and rcp sharing as R13 (its pair m2 = 2*wid + p) -> bit-identical.
            // acc[g][r]: gate g of cell 8q+4*wid+r. Pre-scaled: i,f,o = L*a;
            // g gate = 2L*a; c = 2L*c.
#pragma unroll
            for (int p = 0; p < 2; ++p) {
                const int r0 = 2 * p, r1 = r0 + 1;

                f32x2 eu = { __builtin_amdgcn_exp2f(-acc[0][r0]),
                             __builtin_amdgcn_exp2f(-acc[0][r1]) };  // gate i
                f32x2 ew = { __builtin_amdgcn_exp2f(-acc[1][r0]),
                             __builtin_amdgcn_exp2f(-acc[1][r1]) };  // gate f
                f32x2 ev = { __builtin_amdgcn_exp2f(-acc[2][r0]),
                             __builtin_amdgcn_exp2f(-acc[2][r1]) };  // gate g
                f32x2 ep = { __builtin_amdgcn_exp2f(-acc[3][r0]),
                             __builtin_amdgcn_exp2f(-acc[3][r1]) };  // gate o

                f32x2 A = (eu + 1.0f) * (ev + 1.0f);       // i*g denominator
                f32x2 B = ew + 1.0f;                       // f denominator
                float rA = __builtin_amdgcn_rcpf(A.x * A.y);
                float rB = __builtin_amdgcn_rcpf(B.x * B.y);

                f32x2 t;                                   // 2L*(1-v)
                t.x = fmaf(ev.x, -k2L, k2L);
                t.y = fmaf(ev.y, -k2L, k2L);

                f32x2 fA = f32x2{A.y, A.x} * rA;           // cross factors
                f32x2 fB = f32x2{B.y, B.x} * rB;
                f32x2 tfA = t * fA;
                f32x2 c;                                   // c = f*c + 2L*(i*g)
                c.x = fmaf(c4v[p].x, fB.x, tfA.x);
                c.y = fmaf(c4v[p].y, fB.y, tfA.y);
                c.x = fmaxf(c.x, -35.0f);                  // tanh==-1 to 2e-11 here;
                c.y = fmaxf(c.y, -35.0f);                  // keeps paired C in f32 range
                c4v[p] = c;

                f32x2 es = { __builtin_amdgcn_exp2f(-c.x),
                             __builtin_amdgcn_exp2f(-c.y) };
                f32x2 C = (ep + 1.0f) * (es + 1.0f);       // o*tanh(c) denominator
                float rC = __builtin_amdgcn_rcpf(C.x * C.y);
                f32x2 h = (1.0f - es) * (f32x2{C.y, C.x} * rC);   // h = o*tanh(c)

                // split2 pair via pk pattern (bit-identical to split2)
                u32 wh = pkbf(h.x, h.y);
                f32x2 hif = { f_from_bits(wh << 16), f_from_bits(wh & 0xffff0000u) };
                f32x2 lo = h - hif;
                bh_own[p] = wh;
                bl_own[p] = pkbf(lo.x, lo.y);
            }

            // publish own half for the partner wave's next step
            xch[tc & 1][wid][lane] = make_uint4(bh_own[0], bh_own[1],
                                                bl_own[0], bl_own[1]);
            __syncthreads();

            xg = xgn;
        }
    }

    // ---- epilogue: reconstruct h (hi+lo, ~2^-17) and apply the FC head ----
    __syncthreads();
    float* hfin = (float*)xbuf;            // reuse LDS: [16][33] f32
    {
        FragU HB, LB;
        HB.u[0] = bh_own[0]; HB.u[1] = bh_own[1];
        LB.u[0] = bl_own[0]; LB.u[1] = bl_own[1];
#pragma unroll
        for (int jj = 0; jj < 4; ++jj)
            hfin[n16 * 33 + q * 8 + 4 * wid + jj] = (float)HB.b[jj] + (float)LB.b[jj];
    }
    __syncthreads();
    if (tid < 32) {
        const int m = tid >> 1, o = tid & 1;
        float s = b_fc[o];
#pragma unroll
        for (int j = 0; j < kH; ++j)
            s = fmaf(hfin[m * 33 + j], W_fc[o * kH + j], s);
        out[(size_t)(b0 + m) * 2 + o] = s;
    }
}

extern "C" void kernel_launch(void* const* d_in, const int* in_sizes, int n_in,
                              void* d_out, int out_size, void* d_ws, size_t ws_size,
                              hipStream_t stream) {
    const float* x    = (const float*)d_in[0];
    const float* W_ih = (const float*)d_in[1];
    const float* W_hh = (const float*)d_in[2];
    const float* b_ih = (const float*)d_in[3];
    const float* b_hh = (const float*)d_in[4];
    const float* W_fc = (const float*)d_in[5];
    const float* b_fc = (const float*)d_in[6];
    float* out = (float*)d_out;

    // 16384 batches / 16 per block = 1024 blocks x 2 waves = 2 waves/SIMD
    hipLaunchKernelGGL(lstm_dw, dim3(1024), dim3(128), 0, stream,
                       x, W_ih, W_hh, b_ih, b_hh, W_fc, b_fc, out);
}

// Round 7
// 239.070 us; speedup vs baseline: 1.1015x; 1.1015x over previous
//
#include <hip/hip_runtime.h>

// TemporalLSTM round 16 (gfx950): REVERT to R13 (best measured: ~180.4 us
// per-dispatch mean) and declare the structural floor.
//
// R15 post-mortem (REGRESSED 180 -> 203): 2-wave cell-split doubled
// occupancy (11 -> 20%) but the per-step barrier + LDS exchange put ds_read
// latency on the recurrence critical path and phase-locked the waves ->
// pipe collisions instead of overlap.
//
// Floor analysis (R8-R15, six mechanisms bracketed):
//  - 16384 batches / 16-per-wave = 1024 waves = exactly 1 wave/SIMD chip-wide.
//    Finer splits waste wave-wide tiles AND wave-wide trans lanes (R8);
//    cell splits need per-step sync (R15); 2-waves/SIMD co-residency would
//    idle half the SIMDs (net loss by arithmetic).
//  - Within a wave the step is a true serial dependence: MFMA block (546 cyc,
//    17 cyc/MFMA = 1-wave matrix-pipe floor, proven by R13's exact-neutral
//    stage-major null) -> pointwise (1296 cyc VALU-pipe: 52 trans x 16 at the
//    algebraic floor of 6.5 trans/cell after R9's fusions + ~460 pk'd VALU)
//    -> next MFMA block. R10/R12/R14 manual overlap: all regressed; compiler
//    schedule is already optimal (cf. learn_hip m137/m141).
//  - Memory: 2.3% of HBM peak. Irrelevant.
// Effective floor ~1900-2000 cyc/step ~= 160-167 us; measured 2160 ~= 180 us;
// the last ~10% (handoff stalls) resisted every restructuring attempt.
//
// Structure recap (verified R5): A = weights (resident VGPR frags), B = h.
// Gate-row permutation  tile t8 = hb*4+g :  row m -> R = 32g + 8*(m>>2) + 4*hb + (m&3)
// gives C/D (m=4q+r, n): acc[hb*4+g][r] = gate g, batch col n, j = 8q+4hb+r,
// and the next-step B-frag (B[k][n], k=8q+kk -> h[n][8q+kk]) is the lane's own
// pointwise output. No LDS round-trip, no step barriers. 1024 single-wave blocks.

typedef __bf16 bf16x8 __attribute__((ext_vector_type(8)));
typedef float  f32x4  __attribute__((ext_vector_type(4)));
typedef float  f32x2  __attribute__((ext_vector_type(2)));
typedef unsigned int u32;

constexpr int kT = 200, kIN = 5, kH = 32;
constexpr int CT = 40;   // timesteps of x staged per phase (200 = 5*40)

constexpr float kL  = 1.4426950408889634f;   // log2(e)
constexpr float k2L = 2.8853900817779268f;   // 2*log2(e)

union FragU { bf16x8 v; __bf16 b[8]; unsigned short s[8]; u32 u[4]; uint4 q4; };

__device__ __forceinline__ unsigned short bfbits(__bf16 b) {
    union { __bf16 b; unsigned short s; } u; u.b = b; return u.s;
}
__device__ __forceinline__ void split2(float x, __bf16& hi, __bf16& lo) {
    hi = (__bf16)x;                 // RNE cvt
    lo = (__bf16)(x - (float)hi);   // residual, |lo| <= 2^-9 |x|
}
// pack two f32 -> one u32 of 2xbf16 (RNE per element; canonical cvt_pk shape)
__device__ __forceinline__ u32 pkbf(float a, float b) {
    return (u32)bfbits((__bf16)a) | ((u32)bfbits((__bf16)b) << 16);
}
__device__ __forceinline__ float f_from_bits(u32 x) {
    union { u32 u; float f; } t; t.u = x; return t.f;
}

__global__ __launch_bounds__(64) void lstm_reg9(
    const float* __restrict__ x,     // [B,200,5]
    const float* __restrict__ W_ih,  // [128,5]
    const float* __restrict__ W_hh,  // [128,32]
    const float* __restrict__ b_ih,  // [128]
    const float* __restrict__ b_hh,  // [128]
    const float* __restrict__ W_fc,  // [2,32]
    const float* __restrict__ b_fc,  // [2]
    float* __restrict__ out)         // [B,2]
{
    __shared__ uint4 xbuf[CT][34];   // cols 0..31: x B-frags; 32/33: const quads

    const int lane = threadIdx.x;    // single-wave block
    const int n16  = lane & 15;
    const int q    = lane >> 4;
    const int b0   = blockIdx.x * 16;

    // ---- weight A-frags resident in VGPRs (A[m][k]: m = lane&15, k = q*8+j) ----
    // Scaled by kL (gates i,f,o) or k2L (gate g) BEFORE the hi/lo split, so acc
    // values are exp2-ready.
    bf16x8 whhA_h[8], whhA_l[8], wihA[8];
#pragma unroll
    for (int t8 = 0; t8 < 8; ++t8) {
        const int g  = t8 & 3, hb = t8 >> 2;
        const int R  = g * 32 + 8 * (n16 >> 2) + 4 * hb + (n16 & 3);  // gate row
        const float sc = (g == 2) ? k2L : kL;
        FragU H, L;
#pragma unroll
        for (int j = 0; j < 8; ++j)
            split2(sc * W_hh[R * kH + q * 8 + j], H.b[j], L.b[j]);
        whhA_h[t8] = H.v; whhA_l[t8] = L.v;

        float wr[5];
#pragma unroll
        for (int i = 0; i < 5; ++i) wr[i] = sc * W_ih[R * kIN + i];
        __bf16 bh, bl;
        split2(sc * (b_ih[R] + b_hh[R]), bh, bl);

        FragU F;
        F.u[0] = F.u[1] = F.u[2] = F.u[3] = 0u;
        if (q == 0) {                       // k0..7
#pragma unroll
            for (int i = 0; i < 5; ++i) F.b[i] = (__bf16)wr[i];       // k0..4: Wih_hi
#pragma unroll
            for (int i = 0; i < 3; ++i) F.b[5 + i] = (__bf16)wr[i];   // k5..7: Wih_hi(0..2)
        } else if (q == 1) {                // k8..15
            F.b[0] = (__bf16)wr[3];                                   // k8:  Wih_hi(3)
            F.b[1] = (__bf16)wr[4];                                   // k9:  Wih_hi(4)
#pragma unroll
            for (int i = 0; i < 5; ++i) {                             // k10..14: Wih_lo
                __bf16 hbb, lbb; split2(wr[i], hbb, lbb);
                F.b[2 + i] = lbb;
            }
            F.b[7] = bh;                                              // k15: bias_hi
        } else if (q == 2) {
            F.b[0] = bl;                                              // k16: bias_lo
        }
        wihA[t8] = F.v;
    }

    // ---- const x-frag quads (written once) ----
    for (int t2 = lane; t2 < CT; t2 += 64) {
        xbuf[t2][32] = make_uint4(0x3F80u, 0u, 0u, 0u);   // quad2: k16 B=1.0 (bf16)
        xbuf[t2][33] = make_uint4(0u, 0u, 0u, 0u);        // quad3: zeros
    }

    const int col = (q < 2) ? (n16 * 2 + q) : (30 + q);   // loop-invariant frag column
    const f32x4 zf4 = {0.f, 0.f, 0.f, 0.f};

    // recurrence state, fully in registers. c is in 2L units (c_scaled = 2L*c).
    f32x2 c8v[4] = {{0.f, 0.f}, {0.f, 0.f}, {0.f, 0.f}, {0.f, 0.f}};
    FragU Bh, Bl;                          // h as bf16 hi/lo B-frags
    Bh.u[0] = Bh.u[1] = Bh.u[2] = Bh.u[3] = 0u;
    Bl.u[0] = Bl.u[1] = Bl.u[2] = Bl.u[3] = 0u;

    for (int phase = 0; phase < kT / CT; ++phase) {
        // ---- stage CT steps of x as ready-made B-frags (64 lanes, 16 batches) ----
        {
            const int mm = lane >> 2, pp = lane & 3;       // batch row, 10-step chunk
            const float2* xr2 = (const float2*)(x + (size_t)(b0 + mm) * (kT * kIN)
                                                  + (size_t)(phase * CT + pp * 10) * kIN);
            float xv[50];
#pragma unroll
            for (int i = 0; i < 25; ++i) {
                float2 v = xr2[i];
                xv[2 * i] = v.x; xv[2 * i + 1] = v.y;
            }
#pragma unroll
            for (int s5 = 0; s5 < 10; ++s5) {
                u32 xh[5], xl[5];
#pragma unroll
                for (int i = 0; i < 5; ++i) {
                    __bf16 hbb, lbb; split2(xv[s5 * 5 + i], hbb, lbb);
                    xh[i] = bfbits(hbb); xl[i] = bfbits(lbb);
                }
                uint4 f0 = make_uint4(xh[0] | (xh[1] << 16),
                                      xh[2] | (xh[3] << 16),
                                      xh[4] | (xl[0] << 16),
                                      xl[1] | (xl[2] << 16));
                uint4 f1 = make_uint4(xl[3] | (xl[4] << 16),
                                      xh[0] | (xh[1] << 16),
                                      xh[2] | (xh[3] << 16),
                                      xh[4] | (0x3F80u << 16));   // k15: B = 1.0
                const int tc = pp * 10 + s5;
                xbuf[tc][mm * 2 + 0] = f0;
                xbuf[tc][mm * 2 + 1] = f1;
            }
        }
        __syncthreads();

        FragU xg; xg.q4 = xbuf[0][col];

#pragma unroll 1
        for (int tc = 0; tc < CT; ++tc) {
            // prefetch next step's xg (4 VGPRs; dummy wrap at tc=CT-1, reloaded
            // fresh after the next phase's staging barrier)
            FragU xgn;
            const int tn = (tc + 1 < CT) ? tc + 1 : 0;
            xgn.q4 = xbuf[tn][col];

            // gates: STAGE-MAJOR. 4 stages x 8 independent tiles; per-tile
            // accumulation order (xg -> hh*Bh -> hh*Bl -> hl*Bh) unchanged ->
            // bit-identical, but adjacent MFMAs are independent so the matrix
            // pipe fills at issue rate instead of exposing per-link latency.
            f32x4 acc[8];
#pragma unroll
            for (int t8 = 0; t8 < 8; ++t8)
                acc[t8] = __builtin_amdgcn_mfma_f32_16x16x32_bf16(wihA[t8], xg.v, zf4, 0, 0, 0);
#pragma unroll
            for (int t8 = 0; t8 < 8; ++t8)
                acc[t8] = __builtin_amdgcn_mfma_f32_16x16x32_bf16(whhA_h[t8], Bh.v, acc[t8], 0, 0, 0);
#pragma unroll
            for (int t8 = 0; t8 < 8; ++t8)
                acc[t8] = __builtin_amdgcn_mfma_f32_16x16x32_bf16(whhA_h[t8], Bl.v, acc[t8], 0, 0, 0);
#pragma unroll
            for (int t8 = 0; t8 < 8; ++t8)
                acc[t8] = __builtin_amdgcn_mfma_f32_16x16x32_bf16(whhA_l[t8], Bh.v, acc[t8], 0, 0, 0);

            // pointwise, cells in lane-pairs expressed as float2 so the backend
            // can emit v_pk_{fma,mul,add}_f32. Per-element math order identical
            // to R9. acc values pre-scaled: i,f,o gates = L*a; g gate = 2L*a;
            // c = 2L*c.
#pragma unroll
            for (int m2 = 0; m2 < 4; ++m2) {
                const int ti = (m2 >> 1) * 4;              // tile group (hb*4)
                const int r0 = (m2 & 1) * 2, r1 = r0 + 1;  // acc rows for j0/j1

                f32x2 eu = { __builtin_amdgcn_exp2f(-acc[ti + 0][r0]),
                             __builtin_amdgcn_exp2f(-acc[ti + 0][r1]) };  // gate i
                f32x2 ew = { __builtin_amdgcn_exp2f(-acc[ti + 1][r0]),
                             __builtin_amdgcn_exp2f(-acc[ti + 1][r1]) };  // gate f
                f32x2 ev = { __builtin_amdgcn_exp2f(-acc[ti + 2][r0]),
                             __builtin_amdgcn_exp2f(-acc[ti + 2][r1]) };  // gate g
                f32x2 ep = { __builtin_amdgcn_exp2f(-acc[ti + 3][r0]),
                             __builtin_amdgcn_exp2f(-acc[ti + 3][r1]) };  // gate o

                f32x2 A = (eu + 1.0f) * (ev + 1.0f);       // i*g denominator
                f32x2 B = ew + 1.0f;                       // f denominator
                float rA = __builtin_amdgcn_rcpf(A.x * A.y);
                float rB = __builtin_amdgcn_rcpf(B.x * B.y);

                f32x2 t;                                   // 2L*(1-v), as R9
                t.x = fmaf(ev.x, -k2L, k2L);
                t.y = fmaf(ev.y, -k2L, k2L);

                f32x2 fA = f32x2{A.y, A.x} * rA;           // cross factors
                f32x2 fB = f32x2{B.y, B.x} * rB;
                f32x2 tfA = t * fA;
                f32x2 c;                                   // c = f*c + 2L*(i*g)
                c.x = fmaf(c8v[m2].x, fB.x, tfA.x);
                c.y = fmaf(c8v[m2].y, fB.y, tfA.y);
                c.x = fmaxf(c.x, -35.0f);                  // tanh==-1 to 2e-11 here;
                c.y = fmaxf(c.y, -35.0f);                  // keeps paired C in f32 range
                c8v[m2] = c;

                f32x2 es = { __builtin_amdgcn_exp2f(-c.x),
                             __builtin_amdgcn_exp2f(-c.y) };
                f32x2 C = (ep + 1.0f) * (es + 1.0f);       // o*tanh(c) denominator
                float rC = __builtin_amdgcn_rcpf(C.x * C.y);
                f32x2 h = (1.0f - es) * (f32x2{C.y, C.x} * rC);   // h = o*tanh(c)

                // split2 pair: hi via cvt_pk pattern; (float)hi is exactly the
                // bf16 bits with 16 zero bits appended -> 2 bit-ops, no cvts.
                u32 wh = pkbf(h.x, h.y);
                f32x2 hif = { f_from_bits(wh << 16), f_from_bits(wh & 0xffff0000u) };
                f32x2 lo = h - hif;
                Bh.u[m2] = wh;
                Bl.u[m2] = pkbf(lo.x, lo.y);
            }

            xg = xgn;
        }
    }

    // ---- epilogue: reconstruct h (hi+lo, ~2^-17) and apply the FC head ----
    __syncthreads();
    float* hfin = (float*)xbuf;            // reuse LDS: [16][33] f32
#pragma unroll
    for (int jj = 0; jj < 8; ++jj)
        hfin[n16 * 33 + q * 8 + jj] = (float)Bh.b[jj] + (float)Bl.b[jj];
    __syncthreads();
    if (lane < 32) {
        const int m = lane >> 1, o = lane & 1;
        float s = b_fc[o];
#pragma unroll
        for (int j = 0; j < kH; ++j)
            s = fmaf(hfin[m * 33 + j], W_fc[o * kH + j], s);
        out[(size_t)(b0 + m) * 2 + o] = s;
    }
}

extern "C" void kernel_launch(void* const* d_in, const int* in_sizes, int n_in,
                              void* d_out, int out_size, void* d_ws, size_t ws_size,
                              hipStream_t stream) {
    const float* x    = (const float*)d_in[0];
    const float* W_ih = (const float*)d_in[1];
    const float* W_hh = (const float*)d_in[2];
    const float* b_ih = (const float*)d_in[3];
    const float* b_hh = (const float*)d_in[4];
    const float* W_fc = (const float*)d_in[5];
    const float* b_fc = (const float*)d_in[6];
    float* out = (float*)d_out;

    // 16384 batches / 16 per wave = 1024 single-wave blocks
    hipLaunchKernelGGL(lstm_reg9, dim3(1024), dim3(64), 0, stream,
                       x, W_ih, W_hh, b_ih, b_hh, W_fc, b_fc, out);
}